// Round 11
// baseline (86.427 us; speedup 1.0000x reference)
//
#include <hip/hip_runtime.h>
#include <cstdint>

typedef short bf16x8 __attribute__((ext_vector_type(8)));
typedef float f32x4 __attribute__((ext_vector_type(4)));
typedef uint16_t u16x4 __attribute__((ext_vector_type(4)));

#define MFMA_16x16x32(a, b, c) __builtin_amdgcn_mfma_f32_16x16x32_bf16((a), (b), (c), 0, 0, 0)

static constexpr int BATCH = 2;
static constexpr int HEADS = 12;
static constexpr int BH    = BATCH * HEADS;   // 24
static constexpr int NCTX  = 2048;
static constexpr int DH    = 64;
static constexpr int EMB   = 768;

// 0.125 * log2(e): Q pre-scale so softmax runs in exp2 domain
static constexpr float QSCALE = 0.125f * 1.44269504088896340736f;

// ---------- bf16 helpers (raw-bit, RN rounding) ----------
__device__ __forceinline__ uint16_t f2bf(float x) {
    uint32_t u = __float_as_uint(x);
    u += 0x7FFFu + ((u >> 16) & 1u);
    return (uint16_t)(u >> 16);
}
__device__ __forceinline__ float bf2f(uint16_t h) {
    return __uint_as_float(((uint32_t)h) << 16);
}
__device__ __forceinline__ uint32_t cvt_pk_bf16(float lo, float hi) {
    uint32_t r;
    asm("v_cvt_pk_bf16_f32 %0, %1, %2" : "=v"(r) : "v"(lo), "v"(hi));
    return r;
}

// ---------- merged convert: K (range [0,n4a)) and W (range [n4a,n4a+n4b)) ----------
__global__ void k_cvt2(const float* __restrict__ a, uint16_t* __restrict__ da, int n4a,
                       const float* __restrict__ b2, uint16_t* __restrict__ db, int n4b) {
    int i = blockIdx.x * blockDim.x + threadIdx.x;
    const float* src; uint16_t* dst; int j;
    if (i < n4a) { src = a; dst = da; j = i; }
    else {
        j = i - n4a;
        if (j >= n4b) return;
        src = b2; dst = db;
    }
    float4 v = reinterpret_cast<const float4*>(src)[j];
    u16x4 hv = {f2bf(v.x), f2bf(v.y), f2bf(v.z), f2bf(v.w)};
    reinterpret_cast<u16x4*>(dst)[j] = hv;
}

// ---------- V transpose+convert to PV-fragment layout ----------
// vf[((bh*32 + t)*8 + slot)*512 + l*8 + j] = V[kv=64t+32h+8g+j][d=16f+c]
// where slot=2f+h, l=16g+c. Each k_attn B-fragment load is one fully
// coalesced 1KB instruction.
__global__ __launch_bounds__(256) void k_vt(const float* __restrict__ v,
                                            uint16_t* __restrict__ vt) {
    const int bh = blockIdx.y;
    const int n0 = blockIdx.x * 64;
    const int t  = threadIdx.x;
    __shared__ uint16_t tileT[64][72];   // [d][n_local]

    const int r  = t >> 2;          // n-row within tile (0..63)
    const int cc = (t & 3) * 16;    // d-col base
    const float* vp = v + ((size_t)bh * NCTX + n0 + r) * DH + cc;
#pragma unroll
    for (int u = 0; u < 4; ++u) {
        float4 x = reinterpret_cast<const float4*>(vp)[u];
        tileT[cc + 4 * u + 0][r] = f2bf(x.x);
        tileT[cc + 4 * u + 1][r] = f2bf(x.y);
        tileT[cc + 4 * u + 2][r] = f2bf(x.z);
        tileT[cc + 4 * u + 3][r] = f2bf(x.w);
    }
    __syncthreads();

    const int l2 = t & 63;          // fragment lane
    const int s0 = t >> 6;          // 0..3
    const int gg = l2 >> 4;
    const int c2 = l2 & 15;
    uint16_t* vb = vt + ((size_t)bh * 32 + (n0 >> 6)) * 8 * 512;
#pragma unroll
    for (int u = 0; u < 2; ++u) {
        const int slot = s0 + 4 * u;        // 0..7
        const int f = slot >> 1, h = slot & 1;
        bf16x8 x = *reinterpret_cast<const bf16x8*>(&tileT[f * 16 + c2][h * 32 + 8 * gg]);
        *reinterpret_cast<bf16x8*>(vb + (size_t)slot * 512 + l2 * 8) = x;
    }
}

// ---------- flash attention, split-KV x2 ----------
// grid: (NCTX/64, BH, 2). blockIdx.z selects kv half [z*1024, z*1024+1024).
// 1536 blocks = 6/CU = 24 waves/CU (2x parallelism for latency hiding).
// Single-buffer K LDS (18.4KB -> 6 blocks fit; dbuf was neutral per R8).
// Per-wave code identical to R10; epilogue writes NORMALIZED partial O (bf16)
// plus per-q (m, lsum) f32 for the merge kernel.
__global__ __launch_bounds__(256) void k_attn(
        const float* __restrict__ q, const uint16_t* __restrict__ kb,
        const uint16_t* __restrict__ vf, uint16_t* __restrict__ of,
        float* __restrict__ ml) {
    const int bh = blockIdx.y;
    const int z  = blockIdx.z;
    const int tid = threadIdx.x;
    const int w = tid >> 6;
    const int l = tid & 63;
    const int g = l >> 4;    // 16-lane group 0..3
    const int c = l & 15;

    __shared__ uint16_t K_s[64][72];
    __shared__ uint16_t P_s[4][16][72];   // [wave][q][kv]

    const int q0 = blockIdx.x * 64 + w * 16;
    constexpr int NT = (NCTX / 2) / 64;   // 16 tiles per half

    // Q fragments: load fp32 direct, scale by 0.125*log2e, convert in-reg
    bf16x8 qa[2];
    {
        const float* qp = q + ((size_t)bh * NCTX + q0 + c) * DH + 8 * g;
#pragma unroll
        for (int kf = 0; kf < 2; ++kf) {
            float4 x0 = *reinterpret_cast<const float4*>(qp + kf * 32);
            float4 x1 = *reinterpret_cast<const float4*>(qp + kf * 32 + 4);
            bf16x8 f;
            f[0] = (short)f2bf(x0.x * QSCALE); f[1] = (short)f2bf(x0.y * QSCALE);
            f[2] = (short)f2bf(x0.z * QSCALE); f[3] = (short)f2bf(x0.w * QSCALE);
            f[4] = (short)f2bf(x1.x * QSCALE); f[5] = (short)f2bf(x1.y * QSCALE);
            f[6] = (short)f2bf(x1.z * QSCALE); f[7] = (short)f2bf(x1.w * QSCALE);
            qa[kf] = f;
        }
    }

    f32x4 zero = {0.f, 0.f, 0.f, 0.f};
    f32x4 o[4] = {zero, zero, zero, zero};
    float m = -1e30f;     // running max (log2 units), per q=c (uniform across groups)
    float lsum = 0.f;     // lane-partial softmax denominator for q=c

    // K staging decomposition: 256 thr -> 32 rows x 8 chunks, two row-passes
    const int srow = tid >> 3;      // 0..31
    const int sch  = tid & 7;       // 0..7

    const uint16_t* kb_b = kb + ((size_t)bh * NCTX + z * (NCTX / 2) + srow) * DH + sch * 8;
    // per-lane V fragment base (tile index zt = z*NT + t)
    const uint16_t* vf_b = vf + ((size_t)bh * 32 + z * NT) * 8 * 512 + (size_t)l * 8;

    // prologue: stage K tile 0 of this half
    {
        bf16x8 a0 = *reinterpret_cast<const bf16x8*>(kb_b);
        bf16x8 a1 = *reinterpret_cast<const bf16x8*>(kb_b + 32 * DH);
        *reinterpret_cast<bf16x8*>(&K_s[srow][sch * 8])      = a0;
        *reinterpret_cast<bf16x8*>(&K_s[srow + 32][sch * 8]) = a1;
    }
    __syncthreads();

    for (int t = 0; t < NT; ++t) {
        // issue next-K-tile loads early (hide latency under compute)
        bf16x8 nk0, nk1;
        const bool pf = (t + 1) < NT;
        if (pf) {
            const size_t ko = (size_t)(t + 1) * 64 * DH;
            nk0 = *reinterpret_cast<const bf16x8*>(kb_b + ko);
            nk1 = *reinterpret_cast<const bf16x8*>(kb_b + ko + 32 * DH);
        }

        // issue THIS tile's V fragment loads now (consumed at PV, ~full tile away)
        bf16x8 vr[8];
#pragma unroll
        for (int s2 = 0; s2 < 8; ++s2)
            vr[s2] = *reinterpret_cast<const bf16x8*>(vf_b + ((size_t)t * 8 + s2) * 512);

        // ---- S^T = (K Q^T) single-bf16. s[nf][r] = S[kv=16nf+4g+r][q=c]
        f32x4 s[4] = {zero, zero, zero, zero};
        __builtin_amdgcn_s_setprio(1);
#pragma unroll
        for (int nf = 0; nf < 4; ++nf) {
#pragma unroll
            for (int kf = 0; kf < 2; ++kf) {
                bf16x8 bhf = *reinterpret_cast<const bf16x8*>(&K_s[nf * 16 + c][kf * 32 + 8 * g]);
                s[nf] = MFMA_16x16x32(bhf, qa[kf], s[nf]);
            }
        }
        __builtin_amdgcn_s_setprio(0);

        // ---- per-lane partial max over this lane's 16 kv slots (tree, depth 4)
        float pm0 = fmaxf(fmaxf(s[0][0], s[0][1]), fmaxf(s[0][2], s[0][3]));
        float pm1 = fmaxf(fmaxf(s[1][0], s[1][1]), fmaxf(s[1][2], s[1][3]));
        float pm2 = fmaxf(fmaxf(s[2][0], s[2][1]), fmaxf(s[2][2], s[2][3]));
        float pm3 = fmaxf(fmaxf(s[3][0], s[3][1]), fmaxf(s[3][2], s[3][3]));
        float pmax = fmaxf(fmaxf(pm0, pm1), fmaxf(pm2, pm3));

        // deferred max, shfl-free common path (equivalence: see R9)
        if (!__all(pmax <= m + 11.0f)) {
            float smax = fmaxf(pmax, __shfl_xor(pmax, 16));
            smax = fmaxf(smax, __shfl_xor(smax, 32));
            float mnew = fmaxf(m, smax);
            float corr = __builtin_amdgcn_exp2f(m - mnew);
            m = mnew;
            lsum *= corr;
#pragma unroll
            for (int r = 0; r < 4; ++r) {
                float cr = __shfl(corr, 4 * g + r);   // corr for q-local 4g+r
#pragma unroll
                for (int f = 0; f < 4; ++f) o[f][r] *= cr;
            }
        }

        // p = exp2(s - m); pack pairs and write 4 contiguous kv per lane (b64)
#pragma unroll
        for (int nf = 0; nf < 4; ++nf) {
            float p0 = __builtin_amdgcn_exp2f(s[nf][0] - m);
            float p1 = __builtin_amdgcn_exp2f(s[nf][1] - m);
            float p2 = __builtin_amdgcn_exp2f(s[nf][2] - m);
            float p3 = __builtin_amdgcn_exp2f(s[nf][3] - m);
            lsum += (p0 + p1) + (p2 + p3);
            uint2 pk;
            pk.x = cvt_pk_bf16(p0, p1);
            pk.y = cvt_pk_bf16(p2, p3);
            *reinterpret_cast<uint2*>(&P_s[w][c][16 * nf + 4 * g]) = pk;
        }

        // ---- O += P V (V fragments already in registers)
        bf16x8 pa0 = *reinterpret_cast<const bf16x8*>(&P_s[w][c][8 * g]);
        bf16x8 pa1 = *reinterpret_cast<const bf16x8*>(&P_s[w][c][32 + 8 * g]);
        __builtin_amdgcn_s_setprio(1);
#pragma unroll
        for (int f = 0; f < 4; ++f) {
            o[f] = MFMA_16x16x32(pa0, vr[2 * f],     o[f]);
            o[f] = MFMA_16x16x32(pa1, vr[2 * f + 1], o[f]);
        }
        __builtin_amdgcn_s_setprio(0);

        // ---- single-buffer K rotation: readers done -> overwrite -> visible
        __syncthreads();
        if (pf) {
            *reinterpret_cast<bf16x8*>(&K_s[srow][sch * 8])      = nk0;
            *reinterpret_cast<bf16x8*>(&K_s[srow + 32][sch * 8]) = nk1;
        }
        __syncthreads();
    }

    // ---- epilogue: reduce l, write normalized partial O (bf16) + (m, l) f32
    lsum += __shfl_xor(lsum, 16);
    lsum += __shfl_xor(lsum, 32);
    const float linv = 1.0f / lsum;

    const size_t obase = ((size_t)(z * BH + bh) * NCTX + q0) * DH;
#pragma unroll
    for (int r = 0; r < 4; ++r) {
        float lr = __shfl(linv, 4 * g + r);   // 1/l for q-local 4g+r
#pragma unroll
        for (int f = 0; f < 4; ++f) {
            float v = o[f][r] * lr;
            of[obase + (size_t)(4 * g + r) * DH + f * 16 + c] = f2bf(v);
        }
    }
    if (l < 16) {   // lane l holds m,lsum for q = l (g=0, c=l)
        const size_t mli = 2 * ((size_t)(z * BH + bh) * NCTX + q0 + l);
        ml[mli]     = m;
        ml[mli + 1] = lsum;
    }
}

// ---------- merge the two kv-half partials -> xb [b][q][h*64+d] bf16 ----------
// out = w0*O0 + w1*O1, w_z = l_z*exp2(m_z - M) / sum(...)  (O_z pre-normalized)
__global__ __launch_bounds__(256) void k_mrg(const uint16_t* __restrict__ of,
                                             const float* __restrict__ ml,
                                             uint16_t* __restrict__ xb) {
    const int row = blockIdx.x * 256 + threadIdx.x;   // 0 .. BH*NCTX-1
    const int bh = row >> 11;
    const int qq = row & (NCTX - 1);
    const int b = bh / HEADS, h = bh % HEADS;
    const size_t i0 = (size_t)bh * NCTX + qq;
    const size_t i1 = (size_t)(BH + bh) * NCTX + qq;
    const float m0 = ml[2 * i0], l0 = ml[2 * i0 + 1];
    const float m1 = ml[2 * i1], l1 = ml[2 * i1 + 1];
    const float M = fmaxf(m0, m1);
    float c0 = l0 * __builtin_amdgcn_exp2f(m0 - M);
    float c1 = l1 * __builtin_amdgcn_exp2f(m1 - M);
    const float inv = 1.0f / (c0 + c1);
    c0 *= inv; c1 *= inv;

    const uint16_t* p0 = of + i0 * DH;
    const uint16_t* p1 = of + i1 * DH;
    uint16_t* xp = xb + ((size_t)b * NCTX + qq) * EMB + h * DH;
#pragma unroll
    for (int u = 0; u < 8; ++u) {
        bf16x8 a  = *reinterpret_cast<const bf16x8*>(p0 + 8 * u);
        bf16x8 bb = *reinterpret_cast<const bf16x8*>(p1 + 8 * u);
        bf16x8 o8;
#pragma unroll
        for (int j = 0; j < 8; ++j)
            o8[j] = (short)f2bf(bf2f((uint16_t)a[j]) * c0 + bf2f((uint16_t)bb[j]) * c1);
        *reinterpret_cast<bf16x8*>(xp + 8 * u) = o8;
    }
}

// ---------- projection GEMM: Y[4096x768] = X @ W^T + bias (single-bf16) ----------
// 64-wide k rounds, clamped-index register prefetch (R9, unchanged).
__global__ __launch_bounds__(256) void k_proj(
        const uint16_t* __restrict__ xb, const uint16_t* __restrict__ wb,
        const float* __restrict__ bias, float* __restrict__ out) {
    const int tid = threadIdx.x;
    const int w = tid >> 6;
    const int l = tid & 63;
    const int g = l >> 4;
    const int c = l & 15;
    const int m0 = blockIdx.x * 64 + w * 16;
    const int n0 = blockIdx.y * 64;

    __shared__ uint16_t W_s[64][72];

    f32x4 zero = {0.f, 0.f, 0.f, 0.f};
    f32x4 acc[4] = {zero, zero, zero, zero};

    const int srow = tid >> 2;   // 0..63
    const int sch  = tid & 3;    // 0..3
    constexpr int ROUNDS = EMB / 64;   // 12

    const uint16_t* whp = wb + (size_t)(n0 + srow) * EMB + sch * 8;
    const uint16_t* xhp = xb + (size_t)(m0 + c) * EMB + 8 * g;

    bf16x8 w0 = *reinterpret_cast<const bf16x8*>(whp);
    bf16x8 w1 = *reinterpret_cast<const bf16x8*>(whp + 32);
    bf16x8 a0 = *reinterpret_cast<const bf16x8*>(xhp);
    bf16x8 a1 = *reinterpret_cast<const bf16x8*>(xhp + 32);

    for (int rd = 0; rd < ROUNDS; ++rd) {
        __syncthreads();
        *reinterpret_cast<bf16x8*>(&W_s[srow][sch * 8])      = w0;
        *reinterpret_cast<bf16x8*>(&W_s[srow][32 + sch * 8]) = w1;
        __syncthreads();

        const int rn = (rd + 1 < ROUNDS) ? (rd + 1) : (ROUNDS - 1);
        bf16x8 w0n = *reinterpret_cast<const bf16x8*>(whp + (size_t)rn * 64);
        bf16x8 w1n = *reinterpret_cast<const bf16x8*>(whp + (size_t)rn * 64 + 32);
        bf16x8 a0n = *reinterpret_cast<const bf16x8*>(xhp + (size_t)rn * 64);
        bf16x8 a1n = *reinterpret_cast<const bf16x8*>(xhp + (size_t)rn * 64 + 32);

        __builtin_amdgcn_s_setprio(1);
#pragma unroll
        for (int nf = 0; nf < 4; ++nf) {
            bf16x8 b0 = *reinterpret_cast<const bf16x8*>(&W_s[nf * 16 + c][8 * g]);
            bf16x8 b1 = *reinterpret_cast<const bf16x8*>(&W_s[nf * 16 + c][32 + 8 * g]);
            acc[nf] = MFMA_16x16x32(a0, b0, acc[nf]);
            acc[nf] = MFMA_16x16x32(a1, b1, acc[nf]);
        }
        __builtin_amdgcn_s_setprio(0);

        w0 = w0n; w1 = w1n; a0 = a0n; a1 = a1n;
    }

#pragma unroll
    for (int nf = 0; nf < 4; ++nf) {
#pragma unroll
        for (int r = 0; r < 4; ++r) {
            int row = m0 + g * 4 + r;
            int col = n0 + nf * 16 + c;
            out[(size_t)row * EMB + col] = acc[nf][r] + bias[col];
        }
    }
}

extern "C" void kernel_launch(void* const* d_in, const int* in_sizes, int n_in,
                              void* d_out, int out_size, void* d_ws, size_t ws_size,
                              hipStream_t stream) {
    const float* q    = (const float*)d_in[0];
    const float* k    = (const float*)d_in[1];
    const float* v    = (const float*)d_in[2];
    const float* pw   = (const float*)d_in[3];
    const float* pb   = (const float*)d_in[4];
    float* out = (float*)d_out;

    const size_t nqkv = (size_t)BH * NCTX * DH;     // 3,145,728
    const size_t nx   = (size_t)BATCH * NCTX * EMB; // 3,145,728
    const size_t nw   = (size_t)EMB * EMB;          //   589,824

    uint8_t* ws = (uint8_t*)d_ws;
    uint16_t* kb = (uint16_t*)ws;              ws += nqkv * 2;
    uint16_t* vf = (uint16_t*)ws;              ws += nqkv * 2;
    uint16_t* xb = (uint16_t*)ws;              ws += nx * 2;
    uint16_t* wb = (uint16_t*)ws;              ws += nw * 2;
    uint16_t* of = (uint16_t*)ws;              ws += (size_t)2 * BH * NCTX * DH * 2;
    float*    ml = (float*)ws;                 ws += (size_t)2 * BH * NCTX * 2 * 4;

    // converts: K + W merged (Q handled inside k_attn)
    const int n4k = (int)(nqkv / 4);
    const int n4w = (int)(nw / 4);
    k_cvt2<<<(n4k + n4w + 255) / 256, 256, 0, stream>>>(k, kb, n4k, pw, wb, n4w);
    k_vt<<<dim3(NCTX / 64, BH), 256, 0, stream>>>(v, vf);

    // attention: split-KV x2 (1536 blocks = 6/CU = 24 waves/CU)
    k_attn<<<dim3(NCTX / 64, BH, 2), 256, 0, stream>>>(q, kb, vf, of, ml);

    // merge kv-half partials
    k_mrg<<<(BH * NCTX) / 256, 256, 0, stream>>>(of, ml, xb);

    // projection
    k_proj<<<dim3((BATCH * NCTX) / 64, EMB / 64), 256, 0, stream>>>(xb, wb, pb, out);
}